// Round 1
// baseline (131.876 us; speedup 1.0000x reference)
//
#include <hip/hip_runtime.h>

#define S_DIM 16
#define B_DIM 512
#define H_DIM 2048
#define EPS 1e-8f

typedef short bf16x8 __attribute__((ext_vector_type(8)));
typedef float f32x4 __attribute__((ext_vector_type(4)));

__device__ __forceinline__ unsigned short f2bf(float f) {
    union { float f; unsigned int u; } v; v.f = f;
    unsigned int u = v.u;
    unsigned int r = (u + 0x7fffu + ((u >> 16) & 1u)) >> 16;
    return (unsigned short)r;
}

__device__ __forceinline__ float dot4(const float4& a, const float4& b) {
    return a.x*b.x + a.y*b.y + a.z*b.z + a.w*b.w;
}

// ---------------- Kernel 1: W fp32 -> bf16 ----------------
__global__ __launch_bounds__(256) void convert_w_kernel(
    const float* __restrict__ W, unsigned short* __restrict__ Wb) {
    int i = blockIdx.x * 256 + threadIdx.x;  // float4 index, H*H/4 total
    float4 v = ((const float4*)W)[i];
    ushort4 o;
    o.x = f2bf(v.x); o.y = f2bf(v.y); o.z = f2bf(v.z); o.w = f2bf(v.w);
    ((ushort4*)Wb)[i] = o;
}

// ---------------- Kernel 2: sims + weighted mean -> wRep (bf16) ----------------
// grid: B_DIM blocks, 512 threads (8 waves). Wave w owns s = 2w, 2w+1.
// Each lane holds 8 float4 per row (h = 4*(i*64+lane)). E read exactly once.
__global__ __launch_bounds__(512) void simwrep_kernel(
    const float* __restrict__ OG, const float* __restrict__ E,
    unsigned short* __restrict__ wrep) {
    const int b = blockIdx.x;
    const int t = threadIdx.x;
    const int lane = t & 63;
    const int wave = t >> 6;

    __shared__ float4 buf[8][512];  // 64 KiB

    // OG row + ||og||^2 (each wave redundantly; row is L1-hot after first wave)
    const float4* og4 = (const float4*)(OG + (size_t)b * H_DIM);
    float4 og[8];
    float og2 = 0.f;
    #pragma unroll
    for (int i = 0; i < 8; ++i) {
        og[i] = og4[i * 64 + lane];
        og2 += dot4(og[i], og[i]);
    }
    #pragma unroll
    for (int m = 32; m >= 1; m >>= 1) og2 += __shfl_xor(og2, m, 64);
    const float onorm = sqrtf(og2);

    const int s0 = wave * 2, s1 = wave * 2 + 1;
    const float4* e40 = (const float4*)(E + ((size_t)s0 * B_DIM + b) * H_DIM);
    const float4* e41 = (const float4*)(E + ((size_t)s1 * B_DIM + b) * H_DIM);
    float4 e0[8], e1[8];
    float d0 = 0.f, d1 = 0.f, n0 = 0.f, n1 = 0.f;
    #pragma unroll
    for (int i = 0; i < 8; ++i) {
        e0[i] = e40[i * 64 + lane];
        e1[i] = e41[i * 64 + lane];
        d0 += dot4(e0[i], og[i]);
        n0 += dot4(e0[i], e0[i]);
        d1 += dot4(e1[i], og[i]);
        n1 += dot4(e1[i], e1[i]);
    }
    #pragma unroll
    for (int m = 32; m >= 1; m >>= 1) {
        d0 += __shfl_xor(d0, m, 64);
        n0 += __shfl_xor(n0, m, 64);
        d1 += __shfl_xor(d1, m, 64);
        n1 += __shfl_xor(n1, m, 64);
    }
    const float sim0 = d0 / fmaxf(sqrtf(n0) * onorm, EPS);
    const float sim1 = d1 / fmaxf(sqrtf(n1) * onorm, EPS);

    #pragma unroll
    for (int i = 0; i < 8; ++i) {
        float4 p;
        p.x = e0[i].x * sim0 + e1[i].x * sim1;
        p.y = e0[i].y * sim0 + e1[i].y * sim1;
        p.z = e0[i].z * sim0 + e1[i].z * sim1;
        p.w = e0[i].w * sim0 + e1[i].w * sim1;
        buf[wave][i * 64 + lane] = p;
    }
    __syncthreads();

    // combine 8 wave partials for float4-chunk t, mean over S, emit bf16
    float4 s = buf[0][t];
    #pragma unroll
    for (int w = 1; w < 8; ++w) {
        float4 v = buf[w][t];
        s.x += v.x; s.y += v.y; s.z += v.z; s.w += v.w;
    }
    const float sc = 1.f / (float)S_DIM;
    ushort4 o;
    o.x = f2bf(s.x * sc); o.y = f2bf(s.y * sc);
    o.z = f2bf(s.z * sc); o.w = f2bf(s.w * sc);
    ((ushort4*)wrep)[(size_t)b * (H_DIM / 4) + t] = o;
}

// ---------------- Kernel 3: out = wRep @ W^T + b  (bf16 MFMA, fp32 acc) ----------------
// A: 512x2048 bf16 (K-contig). Bw: 2048x2048 bf16 (rows = out cols, K-contig).
// 64x64 block tile, BK=32, 4 waves each 32x32 (2x2 of 16x16x32).
__global__ __launch_bounds__(256) void gemm_kernel(
    const unsigned short* __restrict__ A, const unsigned short* __restrict__ Bw,
    const float* __restrict__ bias, float* __restrict__ out) {
    const int n0 = blockIdx.x * 64;
    const int m0 = blockIdx.y * 64;

    __shared__ unsigned short As[64][40];  // +8 pad to break 64B stride
    __shared__ unsigned short Bs[64][40];

    const int t = threadIdx.x;
    const int lane = t & 63;
    const int wave = t >> 6;
    const int wm = (wave & 1) * 32;
    const int wn = (wave >> 1) * 32;
    const int lr = t >> 2;   // staging row 0..63
    const int lq = t & 3;    // staging k-quad

    const size_t aoff = (size_t)(m0 + lr) * H_DIM + lq * 8;
    const size_t boff = (size_t)(n0 + lr) * H_DIM + lq * 8;

    f32x4 acc00 = {0.f, 0.f, 0.f, 0.f};
    f32x4 acc01 = {0.f, 0.f, 0.f, 0.f};
    f32x4 acc10 = {0.f, 0.f, 0.f, 0.f};
    f32x4 acc11 = {0.f, 0.f, 0.f, 0.f};

    const int row = lane & 15;
    const int q = lane >> 4;

    uint4 av = *(const uint4*)(A + aoff);
    uint4 bv = *(const uint4*)(Bw + boff);

    for (int k0 = 0; k0 < H_DIM; k0 += 32) {
        *(uint4*)&As[lr][lq * 8] = av;
        *(uint4*)&Bs[lr][lq * 8] = bv;
        __syncthreads();
        if (k0 + 32 < H_DIM) {  // register prefetch of next tiles
            av = *(const uint4*)(A + aoff + k0 + 32);
            bv = *(const uint4*)(Bw + boff + k0 + 32);
        }
        bf16x8 a0 = *(const bf16x8*)&As[wm + row][q * 8];
        bf16x8 a1 = *(const bf16x8*)&As[wm + 16 + row][q * 8];
        bf16x8 b0 = *(const bf16x8*)&Bs[wn + row][q * 8];
        bf16x8 b1 = *(const bf16x8*)&Bs[wn + 16 + row][q * 8];
        acc00 = __builtin_amdgcn_mfma_f32_16x16x32_bf16(a0, b0, acc00, 0, 0, 0);
        acc01 = __builtin_amdgcn_mfma_f32_16x16x32_bf16(a0, b1, acc01, 0, 0, 0);
        acc10 = __builtin_amdgcn_mfma_f32_16x16x32_bf16(a1, b0, acc10, 0, 0, 0);
        acc11 = __builtin_amdgcn_mfma_f32_16x16x32_bf16(a1, b1, acc11, 0, 0, 0);
        __syncthreads();
    }

    // Epilogue: D mapping col=lane&15, row=(lane>>4)*4+reg
    const int col = lane & 15;
    const float bias0 = bias[n0 + wn + col];
    const float bias1 = bias[n0 + wn + 16 + col];
    #pragma unroll
    for (int r = 0; r < 4; ++r) {
        const int mr = q * 4 + r;
        float* o0 = out + (size_t)(m0 + wm + mr) * H_DIM + n0 + wn;
        float* o1 = out + (size_t)(m0 + wm + 16 + mr) * H_DIM + n0 + wn;
        o0[col]      = acc00[r] + bias0;
        o0[16 + col] = acc01[r] + bias1;
        o1[col]      = acc10[r] + bias0;
        o1[16 + col] = acc11[r] + bias1;
    }
}

extern "C" void kernel_launch(void* const* d_in, const int* in_sizes, int n_in,
                              void* d_out, int out_size, void* d_ws, size_t ws_size,
                              hipStream_t stream) {
    const float* OG   = (const float*)d_in[0];
    const float* E    = (const float*)d_in[1];
    const float* W    = (const float*)d_in[2];
    const float* bias = (const float*)d_in[3];
    float* out = (float*)d_out;

    unsigned short* wrep = (unsigned short*)d_ws;               // 512*2048 bf16
    unsigned short* Wb   = wrep + (size_t)B_DIM * H_DIM;        // 2048*2048 bf16

    convert_w_kernel<<<(H_DIM * H_DIM / 4) / 256, 256, 0, stream>>>(W, Wb);
    simwrep_kernel<<<B_DIM, 512, 0, stream>>>(OG, E, wrep);
    gemm_kernel<<<dim3(H_DIM / 64, B_DIM / 64), 256, 0, stream>>>(wrep, Wb, bias, out);
}